// Round 18
// baseline (53.018 us; speedup 1.0000x reference)
//
#include <hip/hip_runtime.h>
#include <math.h>

#define BATCH 64
#define H 512
#define W 512
#define KRAD 15
#define STRIP 64               // output rows per block
#define NSTRIP (H / STRIP)     // 8 strips per image
#define RING 48                // LDS ring slots; live span/group = 39, +8 write-ahead = 47 <= 48

__device__ __forceinline__ float wave_reduce(float v) {
    #pragma unroll
    for (int off = 32; off > 0; off >>= 1) v += __shfl_xor(v, off);
    return v;
}

// f32 -> bf16 bits (round-to-nearest-even)
__device__ __forceinline__ unsigned bf16b(float f) {
    unsigned u = __float_as_uint(f);
    return (u + 0x7FFFu + ((u >> 16) & 1u)) >> 16;
}
__device__ __forceinline__ float fbf16(unsigned short s) {
    return __uint_as_float(((unsigned)s) << 16);
}

__device__ __forceinline__ uint4 pack8(float4 a, float4 b) {
    uint4 wv;
    wv.x = bf16b(a.x) | (bf16b(a.y) << 16);
    wv.y = bf16b(a.z) | (bf16b(a.w) << 16);
    wv.z = bf16b(b.x) | (bf16b(b.y) << 16);
    wv.w = bf16b(b.z) | (bf16b(b.w) << 16);
    return wv;
}
__device__ __forceinline__ void unpack8(uint4 u, float4& a, float4& b) {
    a.x = __uint_as_float(u.x << 16); a.y = __uint_as_float(u.x & 0xffff0000u);
    a.z = __uint_as_float(u.y << 16); a.w = __uint_as_float(u.y & 0xffff0000u);
    b.x = __uint_as_float(u.z << 16); b.y = __uint_as_float(u.z & 0xffff0000u);
    b.z = __uint_as_float(u.w << 16); b.w = __uint_as_float(u.w & 0xffff0000u);
}

__device__ __forceinline__ void load_row(const float* __restrict__ base, int r, int lane,
                                         float4& a, float4& b) {
    if (0 <= r && r < H) {
        const float4* p4 = reinterpret_cast<const float4*>(base + (size_t)r * W + lane * 8);
        a = p4[0]; b = p4[1];
    } else {
        a = make_float4(0.f, 0.f, 0.f, 0.f);
        b = a;
    }
}

// Chain-free 31-wide horizontal box sum of one row (from registers), bf16-pack
// to LDS. Lane L owns x in [8L, 8L+8);
//   out[k] = suffix_{L-2}(k+1) + T_{L-1} + T_L + T_{L+1} + prefix_{L+2}(k-1)
// All 17 shuffles independent; edge-lane masking = zero padding.
__device__ __forceinline__ void scan_store(float4 va, float4 vb, int lane,
                                           unsigned short* dst) {
    float v[8] = {va.x, va.y, va.z, va.w, vb.x, vb.y, vb.z, vb.w};
    float P[8];
    P[0] = v[0];
    #pragma unroll
    for (int k = 1; k < 8; ++k) P[k] = P[k - 1] + v[k];
    const float T = P[7];

    float Tm1 = __shfl_up(T, 1);
    float Tm2 = __shfl_up(T, 2);
    float Tp1 = __shfl_down(T, 1);
    float Pm2[7], Pp2[7];
    #pragma unroll
    for (int k = 0; k < 7; ++k) Pm2[k] = __shfl_up(P[k], 2);
    #pragma unroll
    for (int k = 0; k < 7; ++k) Pp2[k] = __shfl_down(P[k], 2);

    if (lane < 1) Tm1 = 0.f;
    if (lane < 2) {
        Tm2 = 0.f;
        #pragma unroll
        for (int k = 0; k < 7; ++k) Pm2[k] = 0.f;
    }
    if (lane > 62) Tp1 = 0.f;
    if (lane > 61) {
        #pragma unroll
        for (int k = 0; k < 7; ++k) Pp2[k] = 0.f;
    }

    const float C = Tm1 + T + Tp1;
    float o[8];
    o[0] = C + (Tm2 - Pm2[0]);
    #pragma unroll
    for (int k = 1; k < 7; ++k) o[k] = C + (Tm2 - Pm2[k]) + Pp2[k - 1];
    o[7] = C + Pp2[6];

    uint4 wv;
    wv.x = bf16b(o[0]) | (bf16b(o[1]) << 16);
    wv.y = bf16b(o[2]) | (bf16b(o[3]) << 16);
    wv.z = bf16b(o[4]) | (bf16b(o[5]) << 16);
    wv.w = bf16b(o[6]) | (bf16b(o[7]) << 16);
    *reinterpret_cast<uint4*>(dst + lane * 8) = wv;      // 16B, conflict-free
}

// -------- Fused: LDS-staged scan input -> chain-free scan -> 48-slot bf16 ring
// -> vertical window + loss. ONE barrier per group (slot algebra per R11).
// Scan input for group g+1 is loaded in phase B of g and ds_written to a
// double-buffered staging row (same wave produces & consumes -> no barrier,
// no cross-phase register liveness). Phase A reads it from LDS: no global
// load in the lockstep phase at all.
__global__ __launch_bounds__(512) void fused_kernel(const float* __restrict__ pred,
                                                    const float* __restrict__ mask,
                                                    float2* __restrict__ partials) {
    __shared__ unsigned short ring[RING][W];             // 49152 B
    __shared__ unsigned short stag[2][8][W];             // 16384 B (bf16 raw rows)

    const int tid  = threadIdx.x;
    const int wave = tid >> 6;
    const int lane = tid & 63;
    const int img   = blockIdx.x >> 3;                   // NSTRIP = 8
    const int strip = blockIdx.x & 7;
    const int r0 = strip * STRIP;
    const int c  = tid;
    const float* mk = mask + (size_t)img * (H * W);
    const float* pr = pred + (size_t)img * (H * W);

    // Prologue: fill ring slots 0..30 (rows r0-16 .. r0+14)
    #pragma unroll
    for (int gp = 0; gp < 4; ++gp) {
        const int idx = gp * 8 + wave;
        if (idx < 31) {
            float4 la, lb;
            load_row(mk, r0 - 16 + idx, lane, la, lb);
            scan_store(la, lb, lane, &ring[idx][0]);
        }
    }
    // Fill stag[0]: group-0 scan rows r0+15+wave (max 470 < H, always valid)
    {
        float4 la, lb;
        load_row(mk, r0 + 15 + wave, lane, la, lb);
        *reinterpret_cast<uint4*>(&stag[0][wave][lane * 8]) = pack8(la, lb);
    }
    __syncthreads();

    // Initial vertical sum: slots 1..30 (rows r0-15 .. r0+14)
    float vsum = 0.f;
    #pragma unroll
    for (int s = 1; s <= 30; ++s) vsum += fbf16(ring[s][c]);

    float s0 = 0.f, s1 = 0.f;
    const float inv_k2 = 1.0f / 961.0f;
    int sA = 31;   // (8g+31) % 48
    int sB = 0;    //  8g     % 48

    for (int g = 0; g < STRIP / 8; ++g) {
        const int ybase = r0 + 8 * g;
        // Phase A: read staged row from LDS (rows >= H were staged as zeros),
        // scan, store to ring slot (sA+wave) mod 48. No global loads here.
        {
            float4 sva, svb;
            unpack8(*reinterpret_cast<const uint4*>(&stag[g & 1][wave][lane * 8]), sva, svb);
            int slot = sA + wave;
            if (slot >= RING) slot -= RING;
            scan_store(sva, svb, lane, &ring[slot][0]);
        }
        __syncthreads();   // the ONLY barrier per group

        // Phase B: issue this group's m/p loads and next group's scan-row load;
        // math covers their latency; staging write goes last.
        float m[8], p[8];
        #pragma unroll
        for (int i = 0; i < 8; ++i) {
            const int y = ybase + i;
            m[i] = mk[(size_t)y * W + c];
            p[i] = pr[(size_t)y * W + c];
        }
        const bool do_stage = (g + 1 < STRIP / 8);       // wave-uniform
        float4 na, nb;
        if (do_stage) load_row(mk, ybase + 23 + wave, lane, na, nb);  // zero-fills >= H

        float addv[8], subv[8];
        #pragma unroll
        for (int i = 0; i < 8; ++i) {
            int slotA = sA + i;
            if (slotA >= RING) slotA -= RING;
            addv[i] = fbf16(ring[slotA][c]);
            subv[i] = fbf16(ring[sB + i][c]);            // sB+i <= 47, never wraps
        }
        float ws[8];
        {
            float acc = vsum;
            #pragma unroll
            for (int i = 0; i < 8; ++i) { acc += addv[i] - subv[i]; ws[i] = acc; }
            vsum = acc;
        }
        #pragma unroll
        for (int i = 0; i < 8; ++i) {
            const float avg = ws[i] * inv_k2;
            const float w = 1.0f + 5.0f * fabsf(avg - m[i]);

            const float e = __expf(-fabsf(p[i]));        // 1 trans
            const float u = 1.0f + e;
            const float softplus = __logf(u);            // log1p(e); 1 trans
            const float bce = fmaxf(p[i], 0.0f) - p[i] * m[i] + softplus;

            // sigmoid-free IoU: a = (p>=0 ? 1 : e), sig = a/u,
            //   (inter+1)/denom = (a*m + u) / (a*(1-m) + (m+1)*u)  -- single rcp
            const float a = (p[i] >= 0.0f) ? 1.0f : e;
            const float num = a * m[i] + u;
            const float den = a * (1.0f - m[i]) + (m[i] + 1.0f) * u;
            const float iou = 1.0f - num * __builtin_amdgcn_rcpf(den);  // 1 trans

            s0 += w;
            s1 += w * (bce + iou);
        }
        // Staging write: by now the load has had the whole math phase to land.
        if (do_stage)
            *reinterpret_cast<uint4*>(&stag[(g + 1) & 1][wave][lane * 8]) = pack8(na, nb);

        sA += 8; if (sA >= RING) sA -= RING;
        sB += 8; if (sB >= RING) sB -= RING;
        // no tail barrier: RING=48 slack covers the one-group write-ahead
    }

    s0 = wave_reduce(s0);
    s1 = wave_reduce(s1);
    __syncthreads();                                     // all ring reads done
    float2* wacc = reinterpret_cast<float2*>(&ring[0][0]);   // alias: ring dead now
    if (lane == 0) wacc[wave] = make_float2(s0, s1);
    __syncthreads();
    if (tid == 0) {
        float a0 = 0.f, a1 = 0.f;
        #pragma unroll
        for (int i = 0; i < 8; ++i) { a0 += wacc[i].x; a1 += wacc[i].y; }
        partials[blockIdx.x] = make_float2(a0, a1);
    }
}

// -------- Finalize: per-image ratio, mean over 64 images. One wave.
__global__ void finalize_kernel(const float2* __restrict__ partials,
                                float* __restrict__ out) {
    const int lane = threadIdx.x;   // 64 threads, one per image
    float s0 = 0.f, s1 = 0.f;
    #pragma unroll
    for (int j = 0; j < NSTRIP; ++j) {
        const float2 pp = partials[lane * NSTRIP + j];
        s0 += pp.x; s1 += pp.y;
    }
    float q = s1 / s0;
    q = wave_reduce(q);
    if (lane == 0) out[0] = q * (1.0f / (float)BATCH);
}

extern "C" void kernel_launch(void* const* d_in, const int* in_sizes, int n_in,
                              void* d_out, int out_size, void* d_ws, size_t ws_size,
                              hipStream_t stream) {
    const float* pred = (const float*)d_in[0];
    const float* mask = (const float*)d_in[1];
    float2* partials = (float2*)d_ws;   // 512 * 8B

    hipLaunchKernelGGL(fused_kernel, dim3(BATCH * NSTRIP), dim3(512), 0, stream,
                       pred, mask, partials);
    hipLaunchKernelGGL(finalize_kernel, dim3(1), dim3(64), 0, stream,
                       partials, (float*)d_out);
}

// Round 19
// 51.302 us; speedup vs baseline: 1.0334x; 1.0334x over previous
//
#include <hip/hip_runtime.h>
#include <math.h>

#define BATCH 64
#define H 512
#define W 512
#define KRAD 15
#define STRIP 64               // output rows per block
#define NSTRIP (H / STRIP)     // 8 strips per image
#define RING 48                // LDS ring slots; live span/group = 39, +8 write-ahead = 47 <= 48

__device__ __forceinline__ float wave_reduce(float v) {
    #pragma unroll
    for (int off = 32; off > 0; off >>= 1) v += __shfl_xor(v, off);
    return v;
}

// f32 -> bf16 bits (round-to-nearest-even)
__device__ __forceinline__ unsigned bf16b(float f) {
    unsigned u = __float_as_uint(f);
    return (u + 0x7FFFu + ((u >> 16) & 1u)) >> 16;
}
__device__ __forceinline__ float fbf16(unsigned short s) {
    return __uint_as_float(((unsigned)s) << 16);
}

__device__ __forceinline__ void load_row(const float* __restrict__ base, int r, int lane,
                                         float4& a, float4& b) {
    if (0 <= r && r < H) {
        const float4* p4 = reinterpret_cast<const float4*>(base + (size_t)r * W + lane * 8);
        a = p4[0]; b = p4[1];
    } else {
        a = make_float4(0.f, 0.f, 0.f, 0.f);
        b = a;
    }
}

// Chain-free 31-wide horizontal box sum of one row (from registers), bf16-pack
// to LDS. Lane L owns x in [8L, 8L+8);
//   out[k] = suffix_{L-2}(k+1) + T_{L-1} + T_L + T_{L+1} + prefix_{L+2}(k-1)
// All 17 shuffles independent; edge-lane masking = zero padding.
__device__ __forceinline__ void scan_store(float4 va, float4 vb, int lane,
                                           unsigned short* dst) {
    float v[8] = {va.x, va.y, va.z, va.w, vb.x, vb.y, vb.z, vb.w};
    float P[8];
    P[0] = v[0];
    #pragma unroll
    for (int k = 1; k < 8; ++k) P[k] = P[k - 1] + v[k];
    const float T = P[7];

    float Tm1 = __shfl_up(T, 1);
    float Tm2 = __shfl_up(T, 2);
    float Tp1 = __shfl_down(T, 1);
    float Pm2[7], Pp2[7];
    #pragma unroll
    for (int k = 0; k < 7; ++k) Pm2[k] = __shfl_up(P[k], 2);
    #pragma unroll
    for (int k = 0; k < 7; ++k) Pp2[k] = __shfl_down(P[k], 2);

    if (lane < 1) Tm1 = 0.f;
    if (lane < 2) {
        Tm2 = 0.f;
        #pragma unroll
        for (int k = 0; k < 7; ++k) Pm2[k] = 0.f;
    }
    if (lane > 62) Tp1 = 0.f;
    if (lane > 61) {
        #pragma unroll
        for (int k = 0; k < 7; ++k) Pp2[k] = 0.f;
    }

    const float C = Tm1 + T + Tp1;
    float o[8];
    o[0] = C + (Tm2 - Pm2[0]);
    #pragma unroll
    for (int k = 1; k < 7; ++k) o[k] = C + (Tm2 - Pm2[k]) + Pp2[k - 1];
    o[7] = C + Pp2[6];

    uint4 wv;
    wv.x = bf16b(o[0]) | (bf16b(o[1]) << 16);
    wv.y = bf16b(o[2]) | (bf16b(o[3]) << 16);
    wv.z = bf16b(o[4]) | (bf16b(o[5]) << 16);
    wv.w = bf16b(o[6]) | (bf16b(o[7]) << 16);
    *reinterpret_cast<uint4*>(dst + lane * 8) = wv;      // 16B, conflict-free
}

// -------- Fused: chain-free scan -> 48-slot bf16 LDS ring -> vertical window + loss.
// ONE barrier per 8-row group (write-ahead slots provably disjoint; see R11).
// Scan-input row software-pipelined one group ahead (load in phase B of g,
// consume in phase A of g+1; the path crosses no barrier).
// __launch_bounds__(512, 2): min 2 waves/EU -> 1 block/CU -> VGPR budget 256,
// so the prefetch state lives in registers instead of spilling (LDS still
// caps real occupancy at 2-3 blocks/CU; VGPR <= 128 keeps 16 waves/CU legal).
__global__ __launch_bounds__(512, 2) void fused_kernel(const float* __restrict__ pred,
                                                       const float* __restrict__ mask,
                                                       float2* __restrict__ partials) {
    __shared__ unsigned short ring[RING][W];             // 49152 B

    const int tid  = threadIdx.x;
    const int wave = tid >> 6;
    const int lane = tid & 63;
    const int img   = blockIdx.x >> 3;                   // NSTRIP = 8
    const int strip = blockIdx.x & 7;
    const int r0 = strip * STRIP;
    const int c  = tid;
    const float* mk = mask + (size_t)img * (H * W);
    const float* pr = pred + (size_t)img * (H * W);

    // Prologue: fill slots 0..30 (rows r0-16 .. r0+14)
    #pragma unroll
    for (int gp = 0; gp < 4; ++gp) {
        const int idx = gp * 8 + wave;
        if (idx < 31) {
            float4 la, lb;
            load_row(mk, r0 - 16 + idx, lane, la, lb);
            scan_store(la, lb, lane, &ring[idx][0]);
        }
    }
    // Preload group-0 scan input (consumed in first phase A, after the barrier)
    float4 sva, svb;
    load_row(mk, r0 + 15 + wave, lane, sva, svb);
    __syncthreads();

    // Initial vertical sum: slots 1..30 (rows r0-15 .. r0+14)
    float vsum = 0.f;
    #pragma unroll
    for (int s = 1; s <= 30; ++s) vsum += fbf16(ring[s][c]);

    float s0 = 0.f, s1 = 0.f;
    const float inv_k2 = 1.0f / 961.0f;
    int sA = 31;   // (8g+31) % 48
    int sB = 0;    //  8g     % 48

    for (int g = 0; g < STRIP / 8; ++g) {
        const int ybase = r0 + 8 * g;
        // Phase A: scan prefetched row ybase+15+wave into slot (sA+wave) mod 48
        {
            int slot = sA + wave;
            if (slot >= RING) slot -= RING;
            scan_store(sva, svb, lane, &ring[slot][0]);
        }
        __syncthreads();   // the ONLY barrier per group

        // Phase B: issue global loads first (m/p for this group, scan row for next)
        float m[8], p[8];
        #pragma unroll
        for (int i = 0; i < 8; ++i) {
            const int y = ybase + i;
            m[i] = mk[(size_t)y * W + c];
            p[i] = pr[(size_t)y * W + c];
        }
        if (g + 1 < STRIP / 8)
            load_row(mk, ybase + 8 + 15 + wave, lane, sva, svb);   // next group's scan input

        float addv[8], subv[8];
        #pragma unroll
        for (int i = 0; i < 8; ++i) {
            int slotA = sA + i;
            if (slotA >= RING) slotA -= RING;
            addv[i] = fbf16(ring[slotA][c]);
            subv[i] = fbf16(ring[sB + i][c]);            // sB+i <= 47, never wraps
        }
        float ws[8];
        {
            float acc = vsum;
            #pragma unroll
            for (int i = 0; i < 8; ++i) { acc += addv[i] - subv[i]; ws[i] = acc; }
            vsum = acc;
        }
        #pragma unroll
        for (int i = 0; i < 8; ++i) {
            const float avg = ws[i] * inv_k2;
            const float w = 1.0f + 5.0f * fabsf(avg - m[i]);

            const float e = __expf(-fabsf(p[i]));        // 1 trans
            const float u = 1.0f + e;
            const float softplus = __logf(u);            // log1p(e); 1 trans
            const float bce = fmaxf(p[i], 0.0f) - p[i] * m[i] + softplus;

            // sigmoid-free IoU: a = (p>=0 ? 1 : e), sig = a/u,
            //   (inter+1)/denom = (a*m + u) / (a*(1-m) + (m+1)*u)  -- single rcp
            const float a = (p[i] >= 0.0f) ? 1.0f : e;
            const float num = a * m[i] + u;
            const float den = a * (1.0f - m[i]) + (m[i] + 1.0f) * u;
            const float iou = 1.0f - num * __builtin_amdgcn_rcpf(den);  // 1 trans

            s0 += w;
            s1 += w * (bce + iou);
        }
        sA += 8; if (sA >= RING) sA -= RING;
        sB += 8; if (sB >= RING) sB -= RING;
        // no tail barrier: RING=48 slack covers the one-group write-ahead
    }

    s0 = wave_reduce(s0);
    s1 = wave_reduce(s1);
    __syncthreads();                                     // all ring reads done
    float2* wacc = reinterpret_cast<float2*>(&ring[0][0]);   // alias: ring dead now
    if (lane == 0) wacc[wave] = make_float2(s0, s1);
    __syncthreads();
    if (tid == 0) {
        float a0 = 0.f, a1 = 0.f;
        #pragma unroll
        for (int i = 0; i < 8; ++i) { a0 += wacc[i].x; a1 += wacc[i].y; }
        partials[blockIdx.x] = make_float2(a0, a1);
    }
}

// -------- Finalize: per-image ratio, mean over 64 images. One wave.
__global__ void finalize_kernel(const float2* __restrict__ partials,
                                float* __restrict__ out) {
    const int lane = threadIdx.x;   // 64 threads, one per image
    float s0 = 0.f, s1 = 0.f;
    #pragma unroll
    for (int j = 0; j < NSTRIP; ++j) {
        const float2 pp = partials[lane * NSTRIP + j];
        s0 += pp.x; s1 += pp.y;
    }
    float q = s1 / s0;
    q = wave_reduce(q);
    if (lane == 0) out[0] = q * (1.0f / (float)BATCH);
}

extern "C" void kernel_launch(void* const* d_in, const int* in_sizes, int n_in,
                              void* d_out, int out_size, void* d_ws, size_t ws_size,
                              hipStream_t stream) {
    const float* pred = (const float*)d_in[0];
    const float* mask = (const float*)d_in[1];
    float2* partials = (float2*)d_ws;   // 512 * 8B

    hipLaunchKernelGGL(fused_kernel, dim3(BATCH * NSTRIP), dim3(512), 0, stream,
                       pred, mask, partials);
    hipLaunchKernelGGL(finalize_kernel, dim3(1), dim3(64), 0, stream,
                       partials, (float*)d_out);
}

// Round 20
// 41.931 us; speedup vs baseline: 1.2644x; 1.2235x over previous
//
#include <hip/hip_runtime.h>
#include <math.h>

#define BATCH 64
#define H 512
#define W 512
#define KRAD 15
#define STRIP 64               // output rows per block
#define NSTRIP (H / STRIP)     // 8 strips per image
#define RING 48                // LDS ring slots; live span/group = 39, +8 write-ahead = 47 <= 48

__device__ __forceinline__ float wave_reduce(float v) {
    #pragma unroll
    for (int off = 32; off > 0; off >>= 1) v += __shfl_xor(v, off);
    return v;
}

// f32 -> bf16 bits (round-to-nearest-even)
__device__ __forceinline__ unsigned bf16b(float f) {
    unsigned u = __float_as_uint(f);
    return (u + 0x7FFFu + ((u >> 16) & 1u)) >> 16;
}
__device__ __forceinline__ float fbf16(unsigned short s) {
    return __uint_as_float(((unsigned)s) << 16);
}

// One wave: 31-wide horizontal box sum of mask row r (zero padded), bf16-pack
// into ring row dst. Chain-free: lane L owns x in [8L, 8L+8);
//   out[k] = suffix_{L-2}(k+1) + T_{L-1} + T_L + T_{L+1} + prefix_{L+2}(k-1)
// All 17 shuffles independent (no serial wave-scan); edge-lane masking = zero pad.
__device__ __forceinline__ void scan_row(const float* __restrict__ img_base, int r,
                                         int lane, unsigned short* dst) {
    float o[8];
    if (0 <= r && r < H) {
        const float4* in4 = reinterpret_cast<const float4*>(img_base + (size_t)r * W + lane * 8);
        float4 va = in4[0], vb = in4[1];
        float v[8] = {va.x, va.y, va.z, va.w, vb.x, vb.y, vb.z, vb.w};
        float P[8];
        P[0] = v[0];
        #pragma unroll
        for (int k = 1; k < 8; ++k) P[k] = P[k - 1] + v[k];
        const float T = P[7];

        float Tm1 = __shfl_up(T, 1);
        float Tm2 = __shfl_up(T, 2);
        float Tp1 = __shfl_down(T, 1);
        float Pm2[7], Pp2[7];
        #pragma unroll
        for (int k = 0; k < 7; ++k) Pm2[k] = __shfl_up(P[k], 2);
        #pragma unroll
        for (int k = 0; k < 7; ++k) Pp2[k] = __shfl_down(P[k], 2);

        if (lane < 1) Tm1 = 0.f;
        if (lane < 2) {
            Tm2 = 0.f;
            #pragma unroll
            for (int k = 0; k < 7; ++k) Pm2[k] = 0.f;
        }
        if (lane > 62) Tp1 = 0.f;
        if (lane > 61) {
            #pragma unroll
            for (int k = 0; k < 7; ++k) Pp2[k] = 0.f;
        }

        const float C = Tm1 + T + Tp1;
        o[0] = C + (Tm2 - Pm2[0]);
        #pragma unroll
        for (int k = 1; k < 7; ++k) o[k] = C + (Tm2 - Pm2[k]) + Pp2[k - 1];
        o[7] = C + Pp2[6];
    } else {
        #pragma unroll
        for (int k = 0; k < 8; ++k) o[k] = 0.f;
    }
    uint4 wv;
    wv.x = bf16b(o[0]) | (bf16b(o[1]) << 16);
    wv.y = bf16b(o[2]) | (bf16b(o[3]) << 16);
    wv.z = bf16b(o[4]) | (bf16b(o[5]) << 16);
    wv.w = bf16b(o[6]) | (bf16b(o[7]) << 16);
    *reinterpret_cast<uint4*>(dst + lane * 8) = wv;      // 16B, conflict-free
}

// -------- Fused: chain-free scan -> 48-slot bf16 LDS ring -> vertical window + loss.
// ONE barrier per 8-row group (write-ahead slots provably disjoint; see R11).
__global__ __launch_bounds__(512) void fused_kernel(const float* __restrict__ pred,
                                                    const float* __restrict__ mask,
                                                    float2* __restrict__ partials) {
    __shared__ unsigned short ring[RING][W];             // 49152 B

    const int tid  = threadIdx.x;
    const int wave = tid >> 6;
    const int lane = tid & 63;
    const int img   = blockIdx.x >> 3;                   // NSTRIP = 8
    const int strip = blockIdx.x & 7;
    const int r0 = strip * STRIP;
    const int c  = tid;
    const float* mk = mask + (size_t)img * (H * W);
    const float* pr = pred + (size_t)img * (H * W);

    // Prologue: fill slots 0..30 (rows r0-16 .. r0+14)
    #pragma unroll
    for (int gp = 0; gp < 4; ++gp) {
        const int idx = gp * 8 + wave;
        if (idx < 31) scan_row(mk, r0 - 16 + idx, lane, &ring[idx][0]);
    }
    __syncthreads();

    // Initial vertical sum: slots 1..30 (rows r0-15 .. r0+14)
    float vsum = 0.f;
    #pragma unroll
    for (int s = 1; s <= 30; ++s) vsum += fbf16(ring[s][c]);

    float s0 = 0.f, s1 = 0.f;
    const float inv_k2 = 1.0f / 961.0f;
    int sA = 31;   // (8g+31) % 48
    int sB = 0;    //  8g     % 48

    for (int g = 0; g < STRIP / 8; ++g) {
        const int ybase = r0 + 8 * g;
        // Phase A: scan row ybase+15+wave into slot (sA+wave) mod 48
        {
            int slot = sA + wave;
            if (slot >= RING) slot -= RING;
            scan_row(mk, ybase + 15 + wave, lane, &ring[slot][0]);
        }
        __syncthreads();   // the ONLY barrier per group

        // Phase B: issue global m/p loads first (latency hides under LDS+math)
        float m[8], p[8];
        #pragma unroll
        for (int i = 0; i < 8; ++i) {
            const int y = ybase + i;
            m[i] = mk[(size_t)y * W + c];
            p[i] = pr[(size_t)y * W + c];
        }
        float addv[8], subv[8];
        #pragma unroll
        for (int i = 0; i < 8; ++i) {
            int slotA = sA + i;
            if (slotA >= RING) slotA -= RING;
            addv[i] = fbf16(ring[slotA][c]);
            subv[i] = fbf16(ring[sB + i][c]);            // sB+i <= 47, never wraps
        }
        // window sums first (short serial chain), then 8 independent math bodies
        float ws[8];
        {
            float acc = vsum;
            #pragma unroll
            for (int i = 0; i < 8; ++i) { acc += addv[i] - subv[i]; ws[i] = acc; }
            vsum = acc;
        }
        #pragma unroll
        for (int i = 0; i < 8; ++i) {
            const float avg = ws[i] * inv_k2;
            const float w = 1.0f + 5.0f * fabsf(avg - m[i]);

            const float e = __expf(-fabsf(p[i]));        // 1 trans
            const float u = 1.0f + e;
            const float softplus = __logf(u);            // log1p(e); 1 trans
            const float bce = fmaxf(p[i], 0.0f) - p[i] * m[i] + softplus;

            // sigmoid-free IoU: a = (p>=0 ? 1 : e), sig = a/u,
            //   (inter+1)/denom = (a*m + u) / (a*(1-m) + (m+1)*u)  -- single rcp
            const float a = (p[i] >= 0.0f) ? 1.0f : e;
            const float num = a * m[i] + u;
            const float den = a * (1.0f - m[i]) + (m[i] + 1.0f) * u;
            const float iou = 1.0f - num * __builtin_amdgcn_rcpf(den);  // 1 trans

            s0 += w;
            s1 += w * (bce + iou);
        }
        sA += 8; if (sA >= RING) sA -= RING;
        sB += 8; if (sB >= RING) sB -= RING;
        // no tail barrier: RING=48 slack covers the one-group write-ahead
    }

    s0 = wave_reduce(s0);
    s1 = wave_reduce(s1);
    __syncthreads();                                     // all ring reads done
    float2* wacc = reinterpret_cast<float2*>(&ring[0][0]);   // alias: ring dead now
    if (lane == 0) wacc[wave] = make_float2(s0, s1);
    __syncthreads();
    if (tid == 0) {
        float a0 = 0.f, a1 = 0.f;
        #pragma unroll
        for (int i = 0; i < 8; ++i) { a0 += wacc[i].x; a1 += wacc[i].y; }
        partials[blockIdx.x] = make_float2(a0, a1);
    }
}

// -------- Finalize: per-image ratio, mean over 64 images. One wave.
__global__ void finalize_kernel(const float2* __restrict__ partials,
                                float* __restrict__ out) {
    const int lane = threadIdx.x;   // 64 threads, one per image
    float s0 = 0.f, s1 = 0.f;
    #pragma unroll
    for (int j = 0; j < NSTRIP; ++j) {
        const float2 pp = partials[lane * NSTRIP + j];
        s0 += pp.x; s1 += pp.y;
    }
    float q = s1 / s0;
    q = wave_reduce(q);
    if (lane == 0) out[0] = q * (1.0f / (float)BATCH);
}

extern "C" void kernel_launch(void* const* d_in, const int* in_sizes, int n_in,
                              void* d_out, int out_size, void* d_ws, size_t ws_size,
                              hipStream_t stream) {
    const float* pred = (const float*)d_in[0];
    const float* mask = (const float*)d_in[1];
    float2* partials = (float2*)d_ws;   // 512 * 8B

    hipLaunchKernelGGL(fused_kernel, dim3(BATCH * NSTRIP), dim3(512), 0, stream,
                       pred, mask, partials);
    hipLaunchKernelGGL(finalize_kernel, dim3(1), dim3(64), 0, stream,
                       partials, (float*)d_out);
}